// Round 6
// baseline (124.640 us; speedup 1.0000x reference)
//
#include <hip/hip_runtime.h>

#define N 8000
#define C 96
#define C4 24
#define OCH 19
#define NCELL 1000
#define NCH 32
#define HSZ (NCELL*NCH)
#define U1 (1.0f/8000.0f)
#define PAIR_CAP 256

__device__ __forceinline__ int clamp10(int v) { return min(max(v, 0), 9); }

// ---------------- fused prep: prepB (+per-block diff), softmax, copies + ws init ----------------
__global__ void __launch_bounds__(256) k_prep(
    const float* __restrict__ sf, const float* __restrict__ coords,
    const float* __restrict__ posses, const float* __restrict__ sv_prob,
    const float* __restrict__ mf, const float* __restrict__ ori,
    float* __restrict__ w2, float4* __restrict__ alN,
    int* __restrict__ cellB, int* __restrict__ histB,
    float* __restrict__ svp,
    float* __restrict__ o_mf, float* __restrict__ o_ori,
    float4* __restrict__ ck4, int4* __restrict__ wn4, int* __restrict__ flags) {
    int bx = blockIdx.x, tid = threadIdx.x;
    if (bx < 32) {
        __shared__ float sdiff[12];
        if (tid == 0) {
            double M[4][8];
            for (int r = 0; r < 4; ++r)
                for (int c = 0; c < 4; ++c) {
                    M[r][c] = (double)posses[16 + r*4 + c];
                    M[r][4+c] = (r == c) ? 1.0 : 0.0;
                }
            for (int col = 0; col < 4; ++col) {
                int piv = col; double best = fabs(M[col][col]);
                for (int r = col+1; r < 4; ++r) { double v = fabs(M[r][col]); if (v > best) { best = v; piv = r; } }
                if (piv != col) for (int c = 0; c < 8; ++c) { double t = M[col][c]; M[col][c] = M[piv][c]; M[piv][c] = t; }
                double inv = 1.0 / M[col][col];
                for (int c = 0; c < 8; ++c) M[col][c] *= inv;
                for (int r = 0; r < 4; ++r) if (r != col) {
                    double f = M[r][col];
                    for (int c = 0; c < 8; ++c) M[r][c] -= f * M[col][c];
                }
            }
            for (int r = 0; r < 3; ++r)
                for (int c = 0; c < 4; ++c) {
                    double s = 0.0;
                    for (int k = 0; k < 4; ++k) s += M[r][4+k] * (double)posses[k*4 + c];
                    sdiff[r*4 + c] = (float)s;
                }
        }
        __syncthreads();
        int j = bx*256 + tid;
        if (j < N) {
            const float4* s4 = (const float4*)sf + j*C4;
            float s = 0.f;
            for (int kk = 0; kk < C4; ++kk) {
                float4 v = s4[kk];
                s += v.x*v.x; s += v.y*v.y; s += v.z*v.z; s += v.w*v.w;
            }
            w2[j] = sqrtf(s);
            float c0 = coords[j*3], c1 = coords[j*3+1], c2 = coords[j*3+2];
            float a0 = (sdiff[0]*c0 + sdiff[1]*c1) + (sdiff[2]*c2 + sdiff[3]);
            float a1 = (sdiff[4]*c0 + sdiff[5]*c1) + (sdiff[6]*c2 + sdiff[7]);
            float a2 = (sdiff[8]*c0 + sdiff[9]*c1) + (sdiff[10]*c2 + sdiff[11]);
            alN[j] = make_float4(a0, a1, a2, a0*a0 + a1*a1 + a2*a2);
            int cx = clamp10((int)floorf((a0 + 25.f) * 0.2f));
            int cy = clamp10((int)floorf((a1 + 25.f) * 0.2f));
            int cz = clamp10((int)floorf((a2 + 25.f) * 0.2f));
            int cc = (cz*10 + cy)*10 + cx;
            cellB[j] = cc;
            atomicAdd(&histB[cc*NCH + bx], 1);
        }
    } else if (bx < 64) {
        int i = (bx-32)*256 + tid;
        if (i >= N) return;
        float m = -1e30f;
        for (int c = 0; c < OCH; ++c) m = fmaxf(m, sv_prob[i*OCH + c]);
        float e[OCH]; float s = 0.f;
        for (int c = 0; c < OCH; ++c) { e[c] = expf(sv_prob[i*OCH + c] - m); s += e[c]; }
        for (int c = 0; c < OCH; ++c) svp[i*OCH + c] = e[c] / s;
    } else {
        // copies + workspace init (colkey zero, winnerHi|winnerLo 0xFF, flags zero)
        const float4* mf4 = (const float4*)mf;
        const float4* ori4 = (const float4*)ori;
        float4* omf4 = (float4*)o_mf;
        float4* oori4 = (float4*)o_ori;
        float4 z4 = make_float4(0.f, 0.f, 0.f, 0.f);
        int4 f4 = make_int4(-1, -1, -1, -1);
        int t0 = (bx-64)*256 + tid;
        for (int t = t0; t < 206000; t += 192*256) {
            if (t < 192000) omf4[t] = mf4[t];
            else if (t < 198000) oori4[t-192000] = ori4[t-192000];
            else if (t < 202000) ck4[t-198000] = z4;
            else wn4[t-202000] = f4;
        }
        if (bx == 64 && tid < 8) flags[tid] = 0;
    }
}

// ---------------- exclusive scan over [cell][chunk] histogram + cell starts ----------------
__global__ void __launch_bounds__(1024) k_scan(int* __restrict__ h, int* __restrict__ cs) {
    int tid = threadIdx.x;
    int base = tid * 32;
    int v[32]; int s = 0;
    #pragma unroll
    for (int t = 0; t < 32; ++t) { int idx = base + t; int x = (idx < HSZ) ? h[idx] : 0; v[t] = x; s += x; }
    int lane = tid & 63, wv = tid >> 6;
    int x = s;
    for (int off = 1; off < 64; off <<= 1) { int y = __shfl_up(x, off); if (lane >= off) x += y; }
    __shared__ int wtot[16];
    if (lane == 63) wtot[wv] = x;
    __syncthreads();
    int wpre = 0;
    for (int t = 0; t < 16; ++t) if (t < wv) wpre += wtot[t];
    int run = wpre + x - s;
    #pragma unroll
    for (int t = 0; t < 32; ++t) { int idx = base + t; if (idx < HSZ) h[idx] = run; run += v[t]; }
    __syncthreads();
    for (int c = tid; c < NCELL; c += 1024) cs[c] = h[c*NCH];
    if (tid == 0) cs[NCELL] = N;
}

// ---------------- deterministic stable scatter (index + coords only) ----------------
__global__ void k_scatter(const int* __restrict__ cellB, const int* __restrict__ startB,
                          const float4* __restrict__ alN,
                          int* __restrict__ idBR, float4* __restrict__ alR) {
    __shared__ int sc[256];
    int chunk = blockIdx.x, tid = threadIdx.x;
    int gi = chunk*256 + tid;
    int cell = (gi < N) ? cellB[gi] : -1;
    sc[tid] = cell;
    __syncthreads();
    if (gi >= N) return;
    int rank = 0;
    for (int t = 0; t < tid; ++t) rank += (sc[t] == cell);
    int pos = startB[cell*NCH + chunk] + rank;
    idBR[pos] = gi;
    alR[pos] = alN[gi];
}

// ---------------- single dense pass: filter -> compact -> staged coalesced dot -> K -> b -> colmax ----------------
__global__ void __launch_bounds__(256) k_pairs(
    const float4* __restrict__ mf4, const float* __restrict__ ori,
    const float4* __restrict__ alR, const float* __restrict__ w2,
    const float4* __restrict__ sf4, const int* __restrict__ idBR,
    const int* __restrict__ csB,
    unsigned long long* __restrict__ colkey) {
    __shared__ float4 sRow[4][C4];
    __shared__ int bq[4][128];
    __shared__ float bc[4][128];
    __shared__ int sJ[4][PAIR_CAP];
    __shared__ float sK[4][PAIR_CAP];
    __shared__ float4 sFeat[4][16][C4];   // 16-pair staging, XOR-swizzled columns
    __shared__ float sW[4][16];

    int tid = threadIdx.x, lane = tid & 63, w = tid >> 6;
    int i = blockIdx.x * 4 + w;
    if (lane < C4) sRow[w][lane] = mf4[i*C4 + lane];
    __syncthreads();

    float ox = ori[i*3], oy = ori[i*3+1], oz = ori[i*3+2];
    float xnv = ox*ox + oy*oy + oz*oz;
    float s = 0.f;
    for (int kk = 0; kk < C4; ++kk) {
        float4 v = sRow[w][kk];
        s += v.x*v.x; s += v.y*v.y; s += v.z*v.z; s += v.w*v.w;
    }
    float w1v = sqrtf(s);

    int cx = clamp10((int)floorf((ox + 25.f) * 0.2f));
    int cy = clamp10((int)floorf((oy + 25.f) * 0.2f));
    int cz = clamp10((int)floorf((oz + 25.f) * 0.2f));
    int xlo = max(cx-1, 0), xhi = min(cx+1, 9);

    // flatten the 9 (dz,dy) candidate segments into one index space (static unroll)
    int s_[9], l_[9], c_[9];
    int tot = 0;
    #pragma unroll
    for (int t = 0; t < 9; ++t) {
        int z = cz + (t/3) - 1, y = cy + (t%3) - 1;
        bool ok = ((unsigned)z <= 9u) && ((unsigned)y <= 9u);
        int ss = 0, ee = 0;
        if (ok) {
            int cbase = (z*10 + y)*10;
            ss = csB[cbase + xlo];
            ee = csB[cbase + xhi + 1];
        }
        s_[t] = ss; l_[t] = ee - ss; c_[t] = tot; tot += ee - ss;
    }

    int cnt = 0, done = 0, npairs = 0;
    float racc = 0.f;
    unsigned long long lmask = (lane == 0) ? 0ull : (~0ull >> (64 - lane));

    // process up to 16 pairs: coalesced 4-lane-per-row stage into LDS, then 16-lane dot.
    // K math is bit-identical to prior rounds (same element order, same 4-acc pattern).
    auto process16 = [&](int nb) {
        int t = lane >> 2, u = lane & 3;
        if (t < nb) {
            int slot = (done + t) & 127;
            int qq = bq[w][slot];
            int gi = idBR[qq];
            const float4* br = sf4 + gi*C4;
            #pragma unroll
            for (int s2 = 0; s2 < 6; ++s2) {
                int c = s2*4 + u;
                sFeat[w][t][c ^ (t & 7)] = br[c];   // XOR within 8-aligned blocks: stays < 24
            }
            if (u == 0) {
                int sl = npairs + t;
                if (sl < PAIR_CAP) sJ[w][sl] = gi;
                sW[w][t] = w2[gi];
            }
        }
        asm volatile("s_waitcnt lgkmcnt(0)" ::: "memory");   // wave-internal LDS RAW fence
        if (lane < nb) {
            float cdb = bc[w][(done + lane) & 127];
            float ax = 0.f, ay = 0.f, az = 0.f, aw = 0.f;
            #pragma unroll
            for (int kk = 0; kk < C4; ++kk) {
                float4 a = sRow[w][kk];
                float4 b = sFeat[w][lane][kk ^ (lane & 7)];  // logical order kk preserved
                ax += a.x*b.x; ay += a.y*b.y; az += a.z*b.z; aw += a.w*b.w;
            }
            float dot = (ax + ay) + (az + aw);
            float fdc = 1.f - dot / fmaxf(w1v * sW[w][lane], 1e-8f);
            float dist = (1.f + fdc) - expf(-0.5f * cdb);
            float K = expf(-dist / 0.03f);
            racc += K * U1;
            int sl = npairs + lane;
            if (sl < PAIR_CAP) sK[w][sl] = K;
        }
        npairs += nb;
        done += nb;
    };

    for (int f0 = 0; f0 < tot; f0 += 64) {
        int f = f0 + lane;
        bool act = f < tot;
        int q = 0;
        #pragma unroll
        for (int t = 0; t < 9; ++t) {
            bool in = (f >= c_[t]) && (f - c_[t] < l_[t]);
            if (in) q = s_[t] + (f - c_[t]);
        }
        bool pass = false; float cdv = 0.f;
        if (act) {
            float4 aj = alR[q];
            float d = xnv + aj.w - 2.f*(ox*aj.x + oy*aj.y + oz*aj.z);
            cdv = fmaxf(d, 0.f) * 4.f;
            pass = cdv < 100.f;
        }
        unsigned long long m = __ballot(pass);
        if (pass) {
            int slot = (cnt + __popcll(m & lmask)) & 127;
            bq[w][slot] = q; bc[w][slot] = cdv;
        }
        cnt += __popcll(m);
        if (cnt - done >= 64) {
            process16(16); process16(16); process16(16); process16(16);
        }
    }
    while (cnt > done) {
        int nb = cnt - done; if (nb > 16) nb = 16;
        process16(nb);
    }

    for (int off = 32; off; off >>= 1) racc += __shfl_xor(racc, off);
    float bi = U1 / (racc + 1e-16f);

    unsigned long long ikey = (unsigned long long)(unsigned)(N - i);
    int np = min(npairs, PAIR_CAP);
    for (int t = lane; t < np; t += 64) {
        float v = sK[w][t] * bi;
        if (v > 0.f) {
            unsigned long long key = ((unsigned long long)__float_as_uint(v) << 32) | ikey;
            atomicMax(&colkey[sJ[w][t]], key);
        }
    }
}

// ---------------- decode colmax -> winner atomics; wave-aggregated flag atomics ----------------
__global__ void k_post(const unsigned long long* __restrict__ colkey,
                       const float* __restrict__ svp, const int* __restrict__ gt,
                       int* __restrict__ winnerHi, int* __restrict__ winnerLo,
                       int* __restrict__ flags) {
    int j = blockIdx.x * 256 + threadIdx.x;
    int lane = threadIdx.x & 63;
    bool valid = j < N;
    float vv = 0.f; int bidx = 0;
    if (valid) {
        unsigned long long key = colkey[j];
        bidx = key ? (N - (int)(key & 0xffffffffull)) : 0;
        vv = svp[bidx*OCH + gt[j]];
    }
    bool hi = valid && (vv > 0.1f);
    bool nothi = valid && !(vv > 0.1f);
    bool lo = valid && (vv > 0.0f);
    bool notlo = valid && !(vv > 0.0f);
    if (hi) atomicMax(&winnerHi[bidx], j);
    if (lo) atomicMax(&winnerLo[bidx], j);
    unsigned long long m0 = __ballot(hi);
    unsigned long long m1 = __ballot(nothi);
    unsigned long long m2 = __ballot(notlo);
    if (lane == 0) {
        if (m0) atomicOr(&flags[0], 1);
        if (m1) atomicOr(&flags[1], 1);
        if (m2) atomicOr(&flags[2], 1);
    }
}

// ---------------- merged outputs: blocks 0-7 rowsout, block 8 trust ----------------
__global__ void __launch_bounds__(1024) k_final(
    const int* __restrict__ winnerHi, const int* __restrict__ winnerLo,
    const int* __restrict__ flags, const int* __restrict__ gt,
    const float* __restrict__ svp,
    float* __restrict__ o_svp, float* __restrict__ o_pre,
    float* __restrict__ out0, float* __restrict__ out5) {
    int bx = blockIdx.x, tid = threadIdx.x;
    const int* winner = flags[0] ? winnerHi : winnerLo;
    if (bx < 8) {
        int i = bx*1024 + tid;
        if (i >= N) return;
        int w = winner[i];
        float row[OCH];
        if (w >= 0) {
            int g = gt[w];
            for (int c = 0; c < OCH; ++c) row[c] = (c == g) ? 1.f : 0.f;
        } else {
            for (int c = 0; c < OCH; ++c) row[c] = svp[i*OCH + c];
        }
        int p = 0; float m = row[0];
        for (int c = 0; c < OCH; ++c) {
            o_svp[i*OCH + c] = row[c];
            if (c > 0 && row[c] > m) { m = row[c]; p = c; }
        }
        o_pre[i] = (float)p;
    } else {
        __shared__ int wsum[16];
        int off = flags[0] ? (flags[1] ? 1 : 0) : (flags[2] ? 1 : 0);
        for (int p = tid; p < N; p += 1024) { out0[p] = -1.f; out5[p] = -1.f; }
        __syncthreads();
        int base = 0;
        for (int round = 0; round < N; round += 1024) {
            int i = round + tid;
            int pres = (i < N && winner[i] >= 0) ? 1 : 0;
            unsigned long long mask = __ballot(pres);
            int lane = tid & 63;
            int wv = tid >> 6;
            int excl = (lane == 0) ? 0 : __popcll(mask & (~0ull >> (64 - lane)));
            if (lane == 0) wsum[wv] = __popcll(mask);
            __syncthreads();
            int wpre = 0, tot = 0;
            for (int t = 0; t < 16; ++t) { if (t < wv) wpre += wsum[t]; tot += wsum[t]; }
            int pos = base + wpre + excl + off;
            if (pres && pos < N) { out0[pos] = (float)i; out5[pos] = (float)i; }
            base += tot;
            __syncthreads();
        }
    }
}

// ---------------- launch ----------------
extern "C" void kernel_launch(void* const* d_in, const int* in_sizes, int n_in,
                              void* d_out, int out_size, void* d_ws, size_t ws_size,
                              hipStream_t stream) {
    const float* sur_feat   = (const float*)d_in[0];
    const float* sur_coords = (const float*)d_in[1];
    const int*   sur_gt     = (const int*)d_in[2];
    const float* sv_prob    = (const float*)d_in[3];
    const float* mean_feat  = (const float*)d_in[4];
    const float* ori        = (const float*)d_in[5];
    const float* posses     = (const float*)d_in[6];

    float* out = (float*)d_out;
    float* o_trust  = out;
    float* o_mf     = out + 8000;
    float* o_ori    = out + 776000;
    float* o_pre    = out + 800000;
    float* o_svp    = out + 808000;
    float* o_trust2 = out + 960000;

    float* w = (float*)d_ws;
    float* w2 = w;                 w += N;
    float4* alN = (float4*)w;      w += 4*N;
    int* cellB = (int*)w;          w += N;
    int* histB = (int*)w;          w += HSZ;
    unsigned long long* colkey = (unsigned long long*)w;  w += 4*N;
    int* flags = (int*)w;          w += 8;
    int* csB = (int*)w;            w += 1008;
    float* svp = w;                w += N*OCH;
    int* idBR = (int*)w;           w += N;
    float4* alR = (float4*)w;      w += 4*N;
    int* winnerHi = (int*)w;       w += N;
    int* winnerLo = (int*)w;       w += N;

    dim3 b256(256);

    hipMemsetAsync(histB, 0, (size_t)HSZ * 4, stream);

    k_prep<<<256, b256, 0, stream>>>(sur_feat, sur_coords, posses, sv_prob, mean_feat, ori,
                                     w2, alN, cellB, histB, svp, o_mf, o_ori,
                                     (float4*)colkey, (int4*)winnerHi, flags);
    k_scan<<<1, 1024, 0, stream>>>(histB, csB);
    k_scatter<<<32, b256, 0, stream>>>(cellB, histB, alN, idBR, alR);
    k_pairs<<<N/4, b256, 0, stream>>>((const float4*)mean_feat, ori, alR, w2,
                                      (const float4*)sur_feat, idBR, csB, colkey);
    k_post<<<32, b256, 0, stream>>>(colkey, svp, sur_gt, winnerHi, winnerLo, flags);
    k_final<<<9, 1024, 0, stream>>>(winnerHi, winnerLo, flags, sur_gt, svp,
                                    o_svp, o_pre, o_trust, o_trust2);
}